// Round 1
// baseline (861.205 us; speedup 1.0000x reference)
//
#include <hip/hip_runtime.h>

#define E_EDGES 480000
#define N_NODES 30000
#define IN_DIM 256
#define REL_DIM 128
#define OUT_DIM 512
#define CAT_DIM 640  /* 2*IN_DIM + REL_DIM */

typedef float f32x4 __attribute__((ext_vector_type(4)));
typedef __bf16 bf16x8 __attribute__((ext_vector_type(8)));
typedef unsigned short u16x8 __attribute__((ext_vector_type(8)));

static __device__ __forceinline__ unsigned short f2bf(float x) {
    union { float f; unsigned int u; } c; c.f = x;
    unsigned int u = c.u;
    unsigned int r = u + 0x7fffu + ((u >> 16) & 1u);
    return (unsigned short)(r >> 16);
}
static __device__ __forceinline__ float bf2f(unsigned short b) {
    union { unsigned int u; float f; } c; c.u = ((unsigned int)b) << 16;
    return c.f;
}

// ---------------------------------------------------------------------------
// CSR construction
// ---------------------------------------------------------------------------
__global__ void k_count(const int* __restrict__ dst, int* __restrict__ cnt) {
    int e = blockIdx.x * 256 + threadIdx.x;
    if (e < E_EDGES) atomicAdd(&cnt[dst[e]], 1);
}

__global__ void k_scan(const int* __restrict__ cnt, int* __restrict__ off,
                       int* __restrict__ cur) {
    __shared__ int part[1024];
    const int t = threadIdx.x;
    const int CH = (N_NODES + 1023) / 1024;  // 30
    int b = t * CH;
    int e = b + CH; if (e > N_NODES) e = N_NODES;
    if (b > N_NODES) b = N_NODES;
    int s = 0;
    for (int i = b; i < e; ++i) s += cnt[i];
    part[t] = s;
    __syncthreads();
    for (int d = 1; d < 1024; d <<= 1) {
        int v = (t >= d) ? part[t - d] : 0;
        __syncthreads();
        part[t] += v;
        __syncthreads();
    }
    int run = part[t] - s;  // exclusive prefix of this chunk
    for (int i = b; i < e; ++i) { off[i] = run; cur[i] = run; run += cnt[i]; }
    if (t == 1023) off[N_NODES] = run;
}

__global__ void k_fill(const int* __restrict__ dst, int* __restrict__ cur,
                       int* __restrict__ csr) {
    int e = blockIdx.x * 256 + threadIdx.x;
    if (e < E_EDGES) {
        int p = atomicAdd(&cur[dst[e]], 1);
        csr[p] = e;
    }
}

// ---------------------------------------------------------------------------
// Small-K GEMM: C_bf16[M,N] = rowscale * (A_f32[M,K] @ B_f32[K,N] + bias)
// B fragments held in registers (loaded once per wave). One wave = one 16-row
// tile per iteration; NT 16-col tiles (N-chunk = NT*16) per blockIdx.y.
// MFMA 16x16x32 bf16: A lane l holds A[l%16][8*(l/16)+j] (contig-8 along K);
// D lane l reg r -> row (l>>4)*4+r, col l&15 (m89-verified layout).
// ---------------------------------------------------------------------------
template <int K, int NT>
__launch_bounds__(256)
__global__ void gemm_rowtile(const float* __restrict__ Ag,
                             const float* __restrict__ Bg,
                             const float* __restrict__ bias,
                             const float* __restrict__ scale,  // per-row or null
                             unsigned short* __restrict__ Cg,
                             int ldb, int ldc, int mtiles) {
    constexpr int KB = K / 32;
    const int lane = threadIdx.x & 63;
    const int wave = threadIdx.x >> 6;
    const int row16 = lane & 15;
    const int kgrp = lane >> 4;
    const int nc0 = blockIdx.y * (NT * 16);

    // Load B fragments once (small B, L1/L2-resident)
    bf16x8 bfrag[NT][KB];
#pragma unroll
    for (int nt = 0; nt < NT; ++nt) {
        const int col = nc0 + nt * 16 + row16;
#pragma unroll
        for (int kb = 0; kb < KB; ++kb) {
            u16x8 tmp;
#pragma unroll
            for (int j = 0; j < 8; ++j) {
                const int krow = kb * 32 + kgrp * 8 + j;
                tmp[j] = f2bf(Bg[(size_t)krow * ldb + col]);
            }
            bfrag[nt][kb] = __builtin_bit_cast(bf16x8, tmp);
        }
    }

    for (int mt = blockIdx.x * 4 + wave; mt < mtiles; mt += gridDim.x * 4) {
        const float* arow = Ag + (size_t)(mt * 16 + row16) * K + kgrp * 8;
        f32x4 acc[NT] = {};
#pragma unroll
        for (int kb = 0; kb < KB; ++kb) {
            f32x4 a0 = *(const f32x4*)(arow + kb * 32);
            f32x4 a1 = *(const f32x4*)(arow + kb * 32 + 4);
            u16x8 au;
#pragma unroll
            for (int j = 0; j < 4; ++j) { au[j] = f2bf(a0[j]); au[4 + j] = f2bf(a1[j]); }
            bf16x8 af = __builtin_bit_cast(bf16x8, au);
#pragma unroll
            for (int nt = 0; nt < NT; ++nt)
                acc[nt] = __builtin_amdgcn_mfma_f32_16x16x32_bf16(af, bfrag[nt][kb], acc[nt], 0, 0, 0);
        }
#pragma unroll
        for (int nt = 0; nt < NT; ++nt) {
            const int ocol = nc0 + nt * 16 + row16;
            const float bv = bias[ocol];
#pragma unroll
            for (int r = 0; r < 4; ++r) {
                const int orow = mt * 16 + kgrp * 4 + r;
                float v = acc[nt][r] + bv;
                if (scale) v *= scale[orow];
                Cg[(size_t)orow * ldc + ocol] = f2bf(v);
            }
        }
    }
}

// ---------------------------------------------------------------------------
// Gather/reduce: per dst node n,
//   hsum[0:256]   = sum_e natt[src_e]*h2[src_e] + deg*natt[n]*h2[n]
//   hsum[256:384] = sum_e z2[e]
// written as bf16 into A-matrix cols 256..639. 128 threads = 1 node.
// ---------------------------------------------------------------------------
__launch_bounds__(128)
__global__ void k_gather(unsigned short* __restrict__ Amat,
                         const unsigned short* __restrict__ z2,
                         const float* __restrict__ natt,
                         const int* __restrict__ src,
                         const int* __restrict__ off,
                         const int* __restrict__ csr) {
    const int n = blockIdx.x;
    const int t = threadIdx.x;  // 0..127
    const int b = off[n], e = off[n + 1];
    float a0 = 0.f, a1 = 0.f, a2 = 0.f;
    for (int i = b; i < e; ++i) {
        const int eid = csr[i];
        const int s = src[eid];
        const float w = natt[s];
        const unsigned int hv = *(const unsigned int*)(Amat + (size_t)s * CAT_DIM + 2 * t);
        a0 += w * bf2f((unsigned short)(hv & 0xffffu));
        a1 += w * bf2f((unsigned short)(hv >> 16));
        a2 += bf2f(z2[(size_t)eid * REL_DIM + t]);
    }
    const int deg = e - b;
    if (deg > 0) {
        const float w = (float)deg * natt[n];
        const unsigned int hv = *(const unsigned int*)(Amat + (size_t)n * CAT_DIM + 2 * t);
        a0 += w * bf2f((unsigned short)(hv & 0xffffu));
        a1 += w * bf2f((unsigned short)(hv >> 16));
    }
    const unsigned int packed = (unsigned int)f2bf(a0) | ((unsigned int)f2bf(a1) << 16);
    *(unsigned int*)(Amat + (size_t)n * CAT_DIM + IN_DIM + 2 * t) = packed;
    Amat[(size_t)n * CAT_DIM + 2 * IN_DIM + t] = f2bf(a2);
}

// ---------------------------------------------------------------------------
// Final GEMM: out_f32[30000,512] = relu(A_bf16[30000,640] @ Wa_f32->bf16 + ba)
// Wa chunk (32 cols) staged transposed into LDS, +8 ushort pad per row.
// ---------------------------------------------------------------------------
__launch_bounds__(256)
__global__ void gemm_final(const unsigned short* __restrict__ Ag,
                           const float* __restrict__ Wa,
                           const float* __restrict__ ba,
                           float* __restrict__ out, int mtiles) {
    constexpr int KT = CAT_DIM;   // 640
    constexpr int NCH = 32;
    constexpr int LDB = KT + 8;   // 648 ushorts -> 1296B rows (2-way banks, free)
    __shared__ unsigned short Bt[NCH * LDB];
    const int nc0 = blockIdx.y * NCH;
    // coalesced stage: consecutive threads read consecutive n for fixed k
    for (int i = threadIdx.x; i < NCH * KT; i += 256) {
        const int n = i & (NCH - 1);
        const int k = i >> 5;  // NCH == 32
        Bt[n * LDB + k] = f2bf(Wa[(size_t)k * OUT_DIM + nc0 + n]);
    }
    __syncthreads();

    const int lane = threadIdx.x & 63;
    const int wave = threadIdx.x >> 6;
    const int row16 = lane & 15;
    const int kgrp = lane >> 4;

    for (int mt = blockIdx.x * 4 + wave; mt < mtiles; mt += gridDim.x * 4) {
        const unsigned short* arow = Ag + (size_t)(mt * 16 + row16) * KT + kgrp * 8;
        f32x4 acc[2] = {};
#pragma unroll
        for (int kb = 0; kb < KT / 32; ++kb) {
            bf16x8 af = __builtin_bit_cast(bf16x8, *(const u16x8*)(arow + kb * 32));
#pragma unroll
            for (int nt = 0; nt < 2; ++nt) {
                bf16x8 bf = *(const bf16x8*)(&Bt[(nt * 16 + row16) * LDB + kb * 32 + kgrp * 8]);
                acc[nt] = __builtin_amdgcn_mfma_f32_16x16x32_bf16(af, bf, acc[nt], 0, 0, 0);
            }
        }
#pragma unroll
        for (int nt = 0; nt < 2; ++nt) {
            const int ocol = nc0 + nt * 16 + row16;
            const float bv = ba[ocol];
#pragma unroll
            for (int r = 0; r < 4; ++r) {
                const int orow = mt * 16 + kgrp * 4 + r;
                out[(size_t)orow * OUT_DIM + ocol] = fmaxf(acc[nt][r] + bv, 0.0f);
            }
        }
    }
}

// ---------------------------------------------------------------------------
extern "C" void kernel_launch(void* const* d_in, const int* in_sizes, int n_in,
                              void* d_out, int out_size, void* d_ws, size_t ws_size,
                              hipStream_t stream) {
    const float* h    = (const float*)d_in[0];
    const float* natt = (const float*)d_in[1];
    const float* rel  = (const float*)d_in[2];
    const float* eatt = (const float*)d_in[3];
    const float* Wn   = (const float*)d_in[4];
    const float* bn   = (const float*)d_in[5];
    const float* Wr   = (const float*)d_in[6];
    const float* br   = (const float*)d_in[7];
    const float* Wa   = (const float*)d_in[8];
    const float* ba   = (const float*)d_in[9];
    const int* src    = (const int*)d_in[10];
    const int* dst    = (const int*)d_in[11];
    float* out = (float*)d_out;

    // workspace layout (bytes)
    char* base = (char*)d_ws;
    unsigned short* Amat = (unsigned short*)(base);               // 30000*640*2 = 38,400,000
    unsigned short* z2   = (unsigned short*)(base + 38400000);    // 480000*128*2 = 122,880,000
    int* cnt = (int*)(base + 161280000);                          // 120,000
    int* off = (int*)(base + 161400000);                          // 120,004
    int* cur = (int*)(base + 161520128);                          // 120,000
    int* csr = (int*)(base + 161640128);                          // 1,920,000  (total ~163.6 MB)

    // CSR build
    hipMemsetAsync(cnt, 0, N_NODES * sizeof(int), stream);
    k_count<<<(E_EDGES + 255) / 256, 256, 0, stream>>>(dst, cnt);
    k_scan<<<1, 1024, 0, stream>>>(cnt, off, cur);
    k_fill<<<(E_EDGES + 255) / 256, 256, 0, stream>>>(dst, cur, csr);

    // h2 = h @ Wn + bn  -> Amat[:, 0:256] (bf16), ldc = 640
    gemm_rowtile<256, 4><<<dim3(118, 4), 256, 0, stream>>>(
        h, Wn, bn, nullptr, Amat, IN_DIM, CAT_DIM, N_NODES / 16);

    // z2 = edge_att * (rel @ Wr + br) -> z2 (bf16), ldc = 128
    gemm_rowtile<128, 4><<<dim3(938, 2), 256, 0, stream>>>(
        rel, Wr, br, eatt, z2, REL_DIM, REL_DIM, E_EDGES / 16);

    // h_sum -> Amat[:, 256:640]
    k_gather<<<N_NODES, 128, 0, stream>>>(Amat, z2, natt, src, off, csr);

    // out = relu(Amat @ Wa + ba)
    gemm_final<<<dim3(118, 16), 256, 0, stream>>>(Amat, Wa, ba, out, N_NODES / 16);
}

// Round 4
// 669.361 us; speedup vs baseline: 1.2866x; 1.2866x over previous
//
#include <hip/hip_runtime.h>

#define E_EDGES 480000
#define N_NODES 30000
#define IN_DIM 256
#define REL_DIM 128
#define OUT_DIM 512
#define CAT_DIM 640  /* 2*IN_DIM + REL_DIM */
#define MTILES 1875  /* 30000/16 */

typedef float f32x4 __attribute__((ext_vector_type(4)));
typedef __bf16 bf16x8 __attribute__((ext_vector_type(8)));
typedef unsigned short u16x8 __attribute__((ext_vector_type(8)));

static __device__ __forceinline__ unsigned short f2bf(float x) {
    union { float f; unsigned int u; } c; c.f = x;
    unsigned int u = c.u;
    unsigned int r = u + 0x7fffu + ((u >> 16) & 1u);
    return (unsigned short)(r >> 16);
}
static __device__ __forceinline__ float bf2f(unsigned short b) {
    union { unsigned int u; float f; } c; c.u = ((unsigned int)b) << 16;
    return c.f;
}

// ---------------------------------------------------------------------------
// CSR construction
// ---------------------------------------------------------------------------
__global__ void k_count(const int* __restrict__ dst, int* __restrict__ cnt) {
    int e = blockIdx.x * 256 + threadIdx.x;
    if (e < E_EDGES) atomicAdd(&cnt[dst[e]], 1);
}

__global__ void k_scan(const int* __restrict__ cnt, int* __restrict__ off,
                       int* __restrict__ cur) {
    __shared__ int part[1024];
    const int t = threadIdx.x;
    const int CH = (N_NODES + 1023) / 1024;  // 30
    int b = t * CH;
    int e = b + CH; if (e > N_NODES) e = N_NODES;
    if (b > N_NODES) b = N_NODES;
    int s = 0;
    for (int i = b; i < e; ++i) s += cnt[i];
    part[t] = s;
    __syncthreads();
    for (int d = 1; d < 1024; d <<= 1) {
        int v = (t >= d) ? part[t - d] : 0;
        __syncthreads();
        part[t] += v;
        __syncthreads();
    }
    int run = part[t] - s;  // exclusive prefix of this chunk
    for (int i = b; i < e; ++i) { off[i] = run; cur[i] = run; run += cnt[i]; }
    if (t == 1023) off[N_NODES] = run;
}

__global__ void k_fill(const int* __restrict__ dst, int* __restrict__ cur,
                       int* __restrict__ csr) {
    int e = blockIdx.x * 256 + threadIdx.x;
    if (e < E_EDGES) {
        int p = atomicAdd(&cur[dst[e]], 1);
        csr[p] = e;
    }
}

// ---------------------------------------------------------------------------
// Small-K GEMM: C_bf16[M, 64cols] = A_f32[M,K] @ B_f32[K,N](cols nc0..nc0+63)
//   epilogue: v = acc + (rowb ? rowb[row]*bias[col] : bias[col])
// B chunk staged transposed in LDS (bf16, +8 pad). One wave = one 16-row tile.
// MFMA 16x16x32 bf16; D lane l reg r -> row (l>>4)*4+r, col l&15.
// ---------------------------------------------------------------------------
template <int K>
__launch_bounds__(256)
__global__ void gemm_small(const float* __restrict__ Ag,
                           const float* __restrict__ Bg,
                           const float* __restrict__ bias,
                           const float* __restrict__ rowb,
                           unsigned short* __restrict__ Cg,
                           int ldb, int ldc, int mtiles) {
    constexpr int KB = K / 32;
    constexpr int LDB = K + 8;          // ushorts per Bt row
    __shared__ unsigned short Bt[64 * LDB];
    unsigned int* Bt32 = (unsigned int*)Bt;
    const int nc0 = blockIdx.y * 64;

    // stage B[0:K, nc0:nc0+64] -> Bt[n][k], packing 2 k per u32
    for (int idx = threadIdx.x; idx < 64 * (K / 2); idx += 256) {
        const int n = idx & 63;
        const int kp = idx >> 6;
        const float x0 = Bg[(size_t)(2 * kp) * ldb + nc0 + n];
        const float x1 = Bg[(size_t)(2 * kp + 1) * ldb + nc0 + n];
        Bt32[n * (LDB / 2) + kp] = (unsigned int)f2bf(x0) | ((unsigned int)f2bf(x1) << 16);
    }
    __syncthreads();

    const int lane = threadIdx.x & 63;
    const int wave = threadIdx.x >> 6;
    const int row16 = lane & 15;
    const int kgrp = lane >> 4;

    for (int mt = blockIdx.x * 4 + wave; mt < mtiles; mt += gridDim.x * 4) {
        const float* arow = Ag + (size_t)(mt * 16 + row16) * K + kgrp * 8;
        f32x4 acc[4] = {};
#pragma unroll
        for (int kb = 0; kb < KB; ++kb) {
            f32x4 a0 = *(const f32x4*)(arow + kb * 32);
            f32x4 a1 = *(const f32x4*)(arow + kb * 32 + 4);
            u16x8 au;
#pragma unroll
            for (int j = 0; j < 4; ++j) { au[j] = f2bf(a0[j]); au[4 + j] = f2bf(a1[j]); }
            bf16x8 af = __builtin_bit_cast(bf16x8, au);
#pragma unroll
            for (int nt = 0; nt < 4; ++nt) {
                bf16x8 bf = *(const bf16x8*)(&Bt[(nt * 16 + row16) * LDB + kb * 32 + kgrp * 8]);
                acc[nt] = __builtin_amdgcn_mfma_f32_16x16x32_bf16(af, bf, acc[nt], 0, 0, 0);
            }
        }
#pragma unroll
        for (int nt = 0; nt < 4; ++nt) {
            const int ocol = nc0 + nt * 16 + row16;
            const float bv = bias[ocol];
#pragma unroll
            for (int r = 0; r < 4; ++r) {
                const int orow = mt * 16 + kgrp * 4 + r;
                float v = acc[nt][r] + (rowb ? rowb[orow] * bv : bv);
                Cg[(size_t)orow * ldc + ocol] = f2bf(v);
            }
        }
    }
}

// ---------------------------------------------------------------------------
// Gather/reduce over CSR: per dst node n,
//   Amat[n, 256:512] = bf16( sum_e natt[src_e]*h2[src_e] + deg*natt[n]*h2[n] )
//   R[n, 0:128]      = f32 ( sum_e eatt[e]*rel[e] )
//   S[n]             = sum_e eatt[e]
// 128 threads = 1 node (2 h2 cols + 1 rel col per thread).
// ---------------------------------------------------------------------------
__launch_bounds__(128)
__global__ void k_gather(unsigned short* __restrict__ Amat,
                         const float* __restrict__ rel,
                         const float* __restrict__ natt,
                         const float* __restrict__ eatt,
                         const int* __restrict__ src,
                         const int* __restrict__ off,
                         const int* __restrict__ csr,
                         float* __restrict__ R,
                         float* __restrict__ S) {
    const int n = blockIdx.x;
    const int t = threadIdx.x;  // 0..127
    const int b = off[n], e = off[n + 1];
    float a0 = 0.f, a1 = 0.f, ar = 0.f, ae = 0.f;
    for (int i = b; i < e; ++i) {
        const int eid = csr[i];
        const int s = src[eid];
        const float w = natt[s];
        const float ea = eatt[eid];
        const unsigned int hv = *(const unsigned int*)(Amat + (size_t)s * CAT_DIM + 2 * t);
        a0 += w * bf2f((unsigned short)(hv & 0xffffu));
        a1 += w * bf2f((unsigned short)(hv >> 16));
        ar += ea * rel[(size_t)eid * REL_DIM + t];
        ae += ea;
    }
    const int deg = e - b;
    if (deg > 0) {
        const float w = (float)deg * natt[n];
        const unsigned int hv = *(const unsigned int*)(Amat + (size_t)n * CAT_DIM + 2 * t);
        a0 += w * bf2f((unsigned short)(hv & 0xffffu));
        a1 += w * bf2f((unsigned short)(hv >> 16));
    }
    const unsigned int packed = (unsigned int)f2bf(a0) | ((unsigned int)f2bf(a1) << 16);
    *(unsigned int*)(Amat + (size_t)n * CAT_DIM + IN_DIM + 2 * t) = packed;
    R[(size_t)n * REL_DIM + t] = ar;
    if (t == 0) S[n] = ae;
}

// ---------------------------------------------------------------------------
// Final GEMM: out_f32[30000,512] = relu(A_bf16[30000,640] @ Wa + ba)
// BM=128 (8 waves x 16 rows), BN=256 (y=2), K staged in LDS chunks of 64.
// ---------------------------------------------------------------------------
__launch_bounds__(512)
__global__ void gemm_final(const unsigned short* __restrict__ Ag,
                           const float* __restrict__ Wa,
                           const float* __restrict__ ba,
                           float* __restrict__ out) {
    constexpr int KCH = 64;
    constexpr int LDB = KCH + 8;  // 72 ushorts per Bt row
    __shared__ unsigned short Bt[256 * LDB];  // 36.9 KB
    unsigned int* Bt32 = (unsigned int*)Bt;
    const int nc0 = blockIdx.y * 256;

    const int lane = threadIdx.x & 63;
    const int wave = threadIdx.x >> 6;
    const int row16 = lane & 15;
    const int kgrp = lane >> 4;
    const int mt = blockIdx.x * 8 + wave;
    const bool active = (mt < MTILES);

    f32x4 acc[16] = {};
    const unsigned short* arow =
        Ag + (size_t)((active ? mt : 0) * 16 + row16) * CAT_DIM + kgrp * 8;

    for (int kc = 0; kc < CAT_DIM / KCH; ++kc) {
        // stage Wa[kc*64:(kc+1)*64, nc0:nc0+256] transposed, 2 k per u32
        for (int idx = threadIdx.x; idx < 256 * (KCH / 2); idx += 512) {
            const int n = idx & 255;
            const int kp = idx >> 8;
            const int k = kc * KCH + 2 * kp;
            const float x0 = Wa[(size_t)k * OUT_DIM + nc0 + n];
            const float x1 = Wa[(size_t)(k + 1) * OUT_DIM + nc0 + n];
            Bt32[n * (LDB / 2) + kp] = (unsigned int)f2bf(x0) | ((unsigned int)f2bf(x1) << 16);
        }
        __syncthreads();
        if (active) {
#pragma unroll
            for (int kb = 0; kb < 2; ++kb) {
                bf16x8 af = __builtin_bit_cast(bf16x8,
                    *(const u16x8*)(arow + kc * KCH + kb * 32));
#pragma unroll
                for (int nt = 0; nt < 16; ++nt) {
                    bf16x8 bf = *(const bf16x8*)(&Bt[(nt * 16 + row16) * LDB + kb * 32 + kgrp * 8]);
                    acc[nt] = __builtin_amdgcn_mfma_f32_16x16x32_bf16(af, bf, acc[nt], 0, 0, 0);
                }
            }
        }
        __syncthreads();
    }
    if (active) {
#pragma unroll
        for (int nt = 0; nt < 16; ++nt) {
            const int ocol = nc0 + nt * 16 + row16;
            const float bv = ba[ocol];
#pragma unroll
            for (int r = 0; r < 4; ++r) {
                const int orow = mt * 16 + kgrp * 4 + r;
                out[(size_t)orow * OUT_DIM + ocol] = fmaxf(acc[nt][r] + bv, 0.0f);
            }
        }
    }
}

// ---------------------------------------------------------------------------
extern "C" void kernel_launch(void* const* d_in, const int* in_sizes, int n_in,
                              void* d_out, int out_size, void* d_ws, size_t ws_size,
                              hipStream_t stream) {
    const float* h    = (const float*)d_in[0];
    const float* natt = (const float*)d_in[1];
    const float* rel  = (const float*)d_in[2];
    const float* eatt = (const float*)d_in[3];
    const float* Wn   = (const float*)d_in[4];
    const float* bn   = (const float*)d_in[5];
    const float* Wr   = (const float*)d_in[6];
    const float* br   = (const float*)d_in[7];
    const float* Wa   = (const float*)d_in[8];
    const float* ba   = (const float*)d_in[9];
    const int* src    = (const int*)d_in[10];
    const int* dst    = (const int*)d_in[11];
    float* out = (float*)d_out;

    // workspace layout (bytes)
    char* base = (char*)d_ws;
    unsigned short* Amat = (unsigned short*)(base);          // 30000*640*2 = 38,400,000
    float* R = (float*)(base + 38400000);                    // 30000*128*4 = 15,360,000
    float* S = (float*)(base + 53760000);                    // 120,000
    int* cnt = (int*)(base + 53880064);                      // 120,000
    int* off = (int*)(base + 54000064);                      // 120,004
    int* cur = (int*)(base + 54120128);                      // 120,000
    int* csr = (int*)(base + 54240128);                      // 1,920,000

    // CSR build
    hipMemsetAsync(cnt, 0, N_NODES * sizeof(int), stream);
    k_count<<<(E_EDGES + 255) / 256, 256, 0, stream>>>(dst, cnt);
    k_scan<<<1, 1024, 0, stream>>>(cnt, off, cur);
    k_fill<<<(E_EDGES + 255) / 256, 256, 0, stream>>>(dst, cur, csr);

    // h2 = h @ Wn + bn  -> Amat[:, 0:256] (bf16)
    gemm_small<256><<<dim3(469, 4), 256, 0, stream>>>(
        h, Wn, bn, nullptr, Amat, IN_DIM, CAT_DIM, MTILES);

    // gather: Amat[:,256:512] = weighted h2 sums; R = sum eatt*rel; S = sum eatt
    k_gather<<<N_NODES, 128, 0, stream>>>(Amat, rel, natt, eatt, src, off, csr, R, S);

    // Amat[:,512:640] = R @ Wr + S*br
    gemm_small<128><<<dim3(469, 2), 256, 0, stream>>>(
        R, Wr, br, S, Amat + 2 * IN_DIM, REL_DIM, CAT_DIM, MTILES);

    // out = relu(Amat @ Wa + ba)
    gemm_final<<<dim3(235, 2), 512, 0, stream>>>(Amat, Wa, ba, out);
}

// Round 5
// 613.253 us; speedup vs baseline: 1.4043x; 1.0915x over previous
//
#include <hip/hip_runtime.h>

#define E_EDGES 480000
#define N_NODES 30000
#define IN_DIM 256
#define REL_DIM 128
#define OUT_DIM 512
#define CAT_DIM 640  /* 2*IN_DIM + REL_DIM */
#define MTILES 1875  /* 30000/16 */

typedef float f32x4 __attribute__((ext_vector_type(4)));
typedef __bf16 bf16x8 __attribute__((ext_vector_type(8)));
typedef unsigned short u16x8 __attribute__((ext_vector_type(8)));

static __device__ __forceinline__ unsigned short f2bf(float x) {
    union { float f; unsigned int u; } c; c.f = x;
    unsigned int u = c.u;
    unsigned int r = u + 0x7fffu + ((u >> 16) & 1u);
    return (unsigned short)(r >> 16);
}
static __device__ __forceinline__ float bf2f(unsigned short b) {
    union { unsigned int u; float f; } c; c.u = ((unsigned int)b) << 16;
    return c.f;
}

// ---------------------------------------------------------------------------
// CSR construction
// ---------------------------------------------------------------------------
__global__ void k_count(const int* __restrict__ dst, int* __restrict__ cnt) {
    int e = blockIdx.x * 256 + threadIdx.x;
    if (e < E_EDGES) atomicAdd(&cnt[dst[e]], 1);
}

__global__ void k_scan(const int* __restrict__ cnt, int* __restrict__ off,
                       int* __restrict__ cur) {
    __shared__ int part[1024];
    const int t = threadIdx.x;
    const int CH = (N_NODES + 1023) / 1024;  // 30
    int b = t * CH;
    int e = b + CH; if (e > N_NODES) e = N_NODES;
    if (b > N_NODES) b = N_NODES;
    int s = 0;
    for (int i = b; i < e; ++i) s += cnt[i];
    part[t] = s;
    __syncthreads();
    for (int d = 1; d < 1024; d <<= 1) {
        int v = (t >= d) ? part[t - d] : 0;
        __syncthreads();
        part[t] += v;
        __syncthreads();
    }
    int run = part[t] - s;  // exclusive prefix of this chunk
    for (int i = b; i < e; ++i) { off[i] = run; cur[i] = run; run += cnt[i]; }
    if (t == 1023) off[N_NODES] = run;
}

// fill: csr-ordered packed edge records {eid, src, eatt, natt[src]}
__global__ void k_fill(const int* __restrict__ dst, const int* __restrict__ src,
                       const float* __restrict__ eatt, const float* __restrict__ natt,
                       int* __restrict__ cur, int4* __restrict__ ecp) {
    int e = blockIdx.x * 256 + threadIdx.x;
    if (e < E_EDGES) {
        const int d = dst[e];
        const int s = src[e];
        const int p = atomicAdd(&cur[d], 1);
        ecp[p] = make_int4(e, s, __float_as_int(eatt[e]), __float_as_int(natt[s]));
    }
}

// ---------------------------------------------------------------------------
// A-stationary small GEMM: C_bf16[M,NCOLS] = A_f32[M,K] @ B_f32[K,NCOLS]
//   epilogue: v = acc + (rowb ? rowb[row]*bias[col] : bias[col])
// 8 waves/block, one 16-row m-tile per wave, A-frags bf16 in registers (read
// once). Loop over 64-col chunks; B chunk staged transposed in LDS.
// MFMA 16x16x32 bf16; D lane l reg r -> row (l>>4)*4+r, col l&15.
// ---------------------------------------------------------------------------
template <int K, int NCOLS>
__launch_bounds__(512)
__global__ void gemm_As(const float* __restrict__ Ag,
                        const float* __restrict__ Bg,
                        const float* __restrict__ bias,
                        const float* __restrict__ rowb,
                        unsigned short* __restrict__ Cg,
                        int ldc, int mtiles) {
    constexpr int KB = K / 32;
    constexpr int LDB = K + 8;  // ushorts per Bt row
    __shared__ unsigned short Bt[64 * LDB];
    unsigned int* Bt32 = (unsigned int*)Bt;

    const int lane = threadIdx.x & 63;
    const int wave = threadIdx.x >> 6;
    const int row16 = lane & 15;
    const int kgrp = lane >> 4;
    const int mt = blockIdx.x * 8 + wave;
    const bool active = (mt < mtiles);

    // load + convert A fragments once
    bf16x8 af[KB];
    {
        const float* arow = Ag + (size_t)((active ? mt : 0) * 16 + row16) * K + kgrp * 8;
#pragma unroll
        for (int kb = 0; kb < KB; ++kb) {
            f32x4 x0 = *(const f32x4*)(arow + kb * 32);
            f32x4 x1 = *(const f32x4*)(arow + kb * 32 + 4);
            u16x8 au;
#pragma unroll
            for (int j = 0; j < 4; ++j) { au[j] = f2bf(x0[j]); au[4 + j] = f2bf(x1[j]); }
            af[kb] = __builtin_bit_cast(bf16x8, au);
        }
    }

    for (int nc0 = 0; nc0 < NCOLS; nc0 += 64) {
        __syncthreads();  // previous chunk's readers done
        for (int idx = threadIdx.x; idx < 64 * (K / 2); idx += 512) {
            const int n = idx & 63;
            const int kp = idx >> 6;
            const float x0 = Bg[(size_t)(2 * kp) * NCOLS + nc0 + n];
            const float x1 = Bg[(size_t)(2 * kp + 1) * NCOLS + nc0 + n];
            Bt32[n * (LDB / 2) + kp] = (unsigned int)f2bf(x0) | ((unsigned int)f2bf(x1) << 16);
        }
        __syncthreads();
        if (active) {
            f32x4 acc[4] = {};
#pragma unroll
            for (int kb = 0; kb < KB; ++kb) {
#pragma unroll
                for (int nt = 0; nt < 4; ++nt) {
                    bf16x8 bf = *(const bf16x8*)(&Bt[(nt * 16 + row16) * LDB + kb * 32 + kgrp * 8]);
                    acc[nt] = __builtin_amdgcn_mfma_f32_16x16x32_bf16(af[kb], bf, acc[nt], 0, 0, 0);
                }
            }
#pragma unroll
            for (int nt = 0; nt < 4; ++nt) {
                const int ocol = nc0 + nt * 16 + row16;
                const float bv = bias[ocol];
#pragma unroll
                for (int r = 0; r < 4; ++r) {
                    const int orow = mt * 16 + kgrp * 4 + r;
                    float v = acc[nt][r] + (rowb ? rowb[orow] * bv : bv);
                    Cg[(size_t)orow * ldc + ocol] = f2bf(v);
                }
            }
        }
    }
}

// ---------------------------------------------------------------------------
// Gather/reduce over CSR (packed records, dual-issue): per dst node n,
//   Amat[n, 256:512] = bf16( sum_e natt[src_e]*h2[src_e] + deg*natt[n]*h2[n] )
//   R[n, 0:128]      = f32 ( sum_e eatt[e]*rel[e] )
//   S[n]             = sum_e eatt[e]
// ---------------------------------------------------------------------------
__launch_bounds__(128)
__global__ void k_gather(unsigned short* __restrict__ Amat,
                         const float* __restrict__ rel,
                         const float* __restrict__ natt,
                         const int* __restrict__ off,
                         const int4* __restrict__ ecp,
                         float* __restrict__ R,
                         float* __restrict__ S) {
    const int n = blockIdx.x;
    const int t = threadIdx.x;  // 0..127
    const int b = off[n], e = off[n + 1];
    float a0 = 0.f, a1 = 0.f, ar = 0.f, ae = 0.f;
    int i = b;
    for (; i + 2 <= e; i += 2) {
        const int4 p0 = ecp[i];
        const int4 p1 = ecp[i + 1];
        const unsigned int hv0 = *(const unsigned int*)(Amat + (size_t)p0.y * CAT_DIM + 2 * t);
        const float r0 = rel[(size_t)p0.x * REL_DIM + t];
        const unsigned int hv1 = *(const unsigned int*)(Amat + (size_t)p1.y * CAT_DIM + 2 * t);
        const float r1 = rel[(size_t)p1.x * REL_DIM + t];
        const float ea0 = __int_as_float(p0.z), w0 = __int_as_float(p0.w);
        const float ea1 = __int_as_float(p1.z), w1 = __int_as_float(p1.w);
        a0 += w0 * bf2f((unsigned short)(hv0 & 0xffffu)) + w1 * bf2f((unsigned short)(hv1 & 0xffffu));
        a1 += w0 * bf2f((unsigned short)(hv0 >> 16)) + w1 * bf2f((unsigned short)(hv1 >> 16));
        ar += ea0 * r0 + ea1 * r1;
        ae += ea0 + ea1;
    }
    if (i < e) {
        const int4 p0 = ecp[i];
        const unsigned int hv0 = *(const unsigned int*)(Amat + (size_t)p0.y * CAT_DIM + 2 * t);
        const float r0 = rel[(size_t)p0.x * REL_DIM + t];
        const float ea0 = __int_as_float(p0.z), w0 = __int_as_float(p0.w);
        a0 += w0 * bf2f((unsigned short)(hv0 & 0xffffu));
        a1 += w0 * bf2f((unsigned short)(hv0 >> 16));
        ar += ea0 * r0;
        ae += ea0;
    }
    const int deg = e - b;
    if (deg > 0) {
        const float w = (float)deg * natt[n];
        const unsigned int hv = *(const unsigned int*)(Amat + (size_t)n * CAT_DIM + 2 * t);
        a0 += w * bf2f((unsigned short)(hv & 0xffffu));
        a1 += w * bf2f((unsigned short)(hv >> 16));
    }
    const unsigned int packed = (unsigned int)f2bf(a0) | ((unsigned int)f2bf(a1) << 16);
    *(unsigned int*)(Amat + (size_t)n * CAT_DIM + IN_DIM + 2 * t) = packed;
    R[(size_t)n * REL_DIM + t] = ar;
    if (t == 0) S[n] = ae;
}

// ---------------------------------------------------------------------------
// Final GEMM: out_f32[30000,512] = relu(A_bf16[30000,640] @ Wa + ba)
// 8 waves x 2 m-tiles/wave (BM=256), BN=256 (y=2), K in LDS chunks of 64.
// 32 MFMA per 16 ds_read_b128.
// ---------------------------------------------------------------------------
__launch_bounds__(512)
__global__ void gemm_final(const unsigned short* __restrict__ Ag,
                           const float* __restrict__ Wa,
                           const float* __restrict__ ba,
                           float* __restrict__ out) {
    constexpr int KCH = 64;
    constexpr int LDB = KCH + 8;  // 72 ushorts per Bt row
    __shared__ unsigned short Bt[256 * LDB];  // 36.9 KB
    unsigned int* Bt32 = (unsigned int*)Bt;
    const int nc0 = blockIdx.y * 256;

    const int lane = threadIdx.x & 63;
    const int wave = threadIdx.x >> 6;
    const int row16 = lane & 15;
    const int kgrp = lane >> 4;
    const int mt0 = blockIdx.x * 16 + wave * 2;
    const int mt1 = mt0 + 1;
    const bool act0 = (mt0 < MTILES);
    const bool act1 = (mt1 < MTILES);

    f32x4 acc0[16] = {};
    f32x4 acc1[16] = {};
    const unsigned short* arow0 =
        Ag + (size_t)((act0 ? mt0 : 0) * 16 + row16) * CAT_DIM + kgrp * 8;
    const unsigned short* arow1 =
        Ag + (size_t)((act1 ? mt1 : 0) * 16 + row16) * CAT_DIM + kgrp * 8;

    for (int kc = 0; kc < CAT_DIM / KCH; ++kc) {
        __syncthreads();
        for (int idx = threadIdx.x; idx < 256 * (KCH / 2); idx += 512) {
            const int n = idx & 255;
            const int kp = idx >> 8;
            const int k = kc * KCH + 2 * kp;
            const float x0 = Wa[(size_t)k * OUT_DIM + nc0 + n];
            const float x1 = Wa[(size_t)(k + 1) * OUT_DIM + nc0 + n];
            Bt32[n * (LDB / 2) + kp] = (unsigned int)f2bf(x0) | ((unsigned int)f2bf(x1) << 16);
        }
        __syncthreads();
#pragma unroll
        for (int kb = 0; kb < 2; ++kb) {
            bf16x8 a0 = __builtin_bit_cast(bf16x8, *(const u16x8*)(arow0 + kc * KCH + kb * 32));
            bf16x8 a1 = __builtin_bit_cast(bf16x8, *(const u16x8*)(arow1 + kc * KCH + kb * 32));
#pragma unroll
            for (int nt = 0; nt < 16; ++nt) {
                bf16x8 bf = *(const bf16x8*)(&Bt[(nt * 16 + row16) * LDB + kb * 32 + kgrp * 8]);
                acc0[nt] = __builtin_amdgcn_mfma_f32_16x16x32_bf16(a0, bf, acc0[nt], 0, 0, 0);
                acc1[nt] = __builtin_amdgcn_mfma_f32_16x16x32_bf16(a1, bf, acc1[nt], 0, 0, 0);
            }
        }
    }
    if (act0) {
#pragma unroll
        for (int nt = 0; nt < 16; ++nt) {
            const int ocol = nc0 + nt * 16 + row16;
            const float bv = ba[ocol];
#pragma unroll
            for (int r = 0; r < 4; ++r) {
                const int orow = mt0 * 16 + kgrp * 4 + r;
                out[(size_t)orow * OUT_DIM + ocol] = fmaxf(acc0[nt][r] + bv, 0.0f);
            }
        }
    }
    if (act1) {
#pragma unroll
        for (int nt = 0; nt < 16; ++nt) {
            const int ocol = nc0 + nt * 16 + row16;
            const float bv = ba[ocol];
#pragma unroll
            for (int r = 0; r < 4; ++r) {
                const int orow = mt1 * 16 + kgrp * 4 + r;
                out[(size_t)orow * OUT_DIM + ocol] = fmaxf(acc1[nt][r] + bv, 0.0f);
            }
        }
    }
}

// ---------------------------------------------------------------------------
extern "C" void kernel_launch(void* const* d_in, const int* in_sizes, int n_in,
                              void* d_out, int out_size, void* d_ws, size_t ws_size,
                              hipStream_t stream) {
    const float* h    = (const float*)d_in[0];
    const float* natt = (const float*)d_in[1];
    const float* rel  = (const float*)d_in[2];
    const float* eatt = (const float*)d_in[3];
    const float* Wn   = (const float*)d_in[4];
    const float* bn   = (const float*)d_in[5];
    const float* Wr   = (const float*)d_in[6];
    const float* br   = (const float*)d_in[7];
    const float* Wa   = (const float*)d_in[8];
    const float* ba   = (const float*)d_in[9];
    const int* src    = (const int*)d_in[10];
    const int* dst    = (const int*)d_in[11];
    float* out = (float*)d_out;

    // workspace layout (bytes)
    char* base = (char*)d_ws;
    unsigned short* Amat = (unsigned short*)(base);          // 30000*640*2 = 38,400,000
    float* R = (float*)(base + 38400000);                    // 30000*128*4 = 15,360,000
    float* S = (float*)(base + 53760000);                    // 120,000
    int* cnt = (int*)(base + 53880064);                      // 120,000
    int* off = (int*)(base + 54000064);                      // 120,004
    int* cur = (int*)(base + 54120128);                      // 120,000
    int4* ecp = (int4*)(base + 54240128);                    // 480000*16 = 7,680,000

    // CSR build
    hipMemsetAsync(cnt, 0, N_NODES * sizeof(int), stream);
    k_count<<<(E_EDGES + 255) / 256, 256, 0, stream>>>(dst, cnt);
    k_scan<<<1, 1024, 0, stream>>>(cnt, off, cur);
    k_fill<<<(E_EDGES + 255) / 256, 256, 0, stream>>>(dst, src, eatt, natt, cur, ecp);

    // h2 = h @ Wn + bn  -> Amat[:, 0:256] (bf16)
    gemm_As<256, 256><<<235, 512, 0, stream>>>(h, Wn, bn, nullptr, Amat, CAT_DIM, MTILES);

    // gather: Amat[:,256:512] = weighted h2 sums; R = sum eatt*rel; S = sum eatt
    k_gather<<<N_NODES, 128, 0, stream>>>(Amat, rel, natt, off, ecp, R, S);

    // Amat[:,512:640] = R @ Wr + S*br
    gemm_As<128, 128><<<235, 512, 0, stream>>>(R, Wr, br, S, Amat + 2 * IN_DIM, CAT_DIM, MTILES);

    // out = relu(Amat @ Wa + ba)
    gemm_final<<<dim3(118, 2), 512, 0, stream>>>(Amat, Wa, ba, out);
}